// Round 17
// baseline (98.106 us; speedup 1.0000x reference)
//
#include <hip/hip_runtime.h>
#include <math.h>

#define NN 512
#define MM 100
#define TPB 256
#define ROWS_OUT 4            // output rows per strip
#define ROWS_LDS 14           // FIXED staged window (28672 B, 7 DMA ops/wave)
#define PLANES_PER_BLOCK 8

typedef float f32x2 __attribute__((ext_vector_type(2)));
typedef unsigned int u32;
typedef u32 u32x2 __attribute__((ext_vector_type(2)));
typedef u32 u32x4 __attribute__((ext_vector_type(4)));

#define AS1 __attribute__((address_space(1)))
#define AS3 __attribute__((address_space(3)))

__device__ __host__ inline int win_r0(int y0) {
    int r = y0 - 5; if (r < 0) r = 0; if (r > NN - ROWS_LDS) r = NN - ROWS_LDS;
    return r;
}

// ws layout (floats): B_u[51200] | B_v[51200] | pk[2*262144 u32]

__global__ void bcoef_kernel(const float* __restrict__ c_u,
                             const float* __restrict__ c_v,
                             float* __restrict__ B_u,
                             float* __restrict__ B_v) {
    __shared__ float sSt[MM];
    int x = blockIdx.x;
    int j = threadIdx.x;
    if (j < MM) {
        double arg = M_PI * ((double)x / (double)(NN - 1)) * (double)(j + 1);
        sSt[j] = (float)sin(arg);
    }
    __syncthreads();
    if (j >= MM) return;
    float au = 0.f, av = 0.f;
    for (int i = 0; i < MM; ++i) {
        int i1 = i + 1, j1 = j + 1;
        int r2i = i1 * i1 + j1 * j1;
        float w = (r2i <= 10100) ? (1.0f / sqrtf((float)r2i)) : 0.0f;
        float sw = sSt[i] * w;
        au += sw * c_u[i * MM + j];
        av += sw * c_v[i * MM + j];
    }
    B_u[j * NN + x] = au;
    B_v[j * NN + x] = av;
}

// Col-tiled field+table: 512 blocks (strip x 4 col-tiles) -> full GPU
// (was 128 blocks = half idle, ~10us). Thread owns 2 rows x 1 col.
// FIXED 14-row window (r0 = clamp(4*strip-5)): no reduction, no strip_tab.
// +-5 dy clamp verified no-op (R15/R16 absmax identical 0.015625).
// pk[pix] = { (yf-r0)<<9|xf | ((yc-r0)<<9|xf)<<16, xv_u16 | yv_u16<<16 }.
__global__ __launch_bounds__(256)
void field_weights_kernel(const float* __restrict__ B_u,
                          const float* __restrict__ B_v,
                          float scale,
                          u32x2* __restrict__ pk) {
    __shared__ float sS[4 * MM];
    int t = threadIdx.x;
    int strip = blockIdx.x >> 2;
    int x0 = (blockIdx.x & 3) << 7;
    int y0 = strip * ROWS_OUT;

    for (int i = t; i < 4 * MM; i += 256) {
        int r = i / MM, j = i % MM;
        double arg = M_PI * ((double)(y0 + r) / (double)(NN - 1)) * (double)(j + 1);
        sS[i] = (float)sin(arg);
    }
    __syncthreads();

    int c = t & 127, h = t >> 7;      // col within tile, row-pair index
    int x = x0 + c;
    float au0 = 0.f, au1 = 0.f, av0 = 0.f, av1 = 0.f;
    const float* sh = sS + (2 * h) * MM;
    for (int j = 0; j < MM; ++j) {
        float bu = B_u[j * NN + x];
        float bv = B_v[j * NN + x];
        float s0 = sh[j];
        float s1 = sh[MM + j];
        au0 += bu * s0; au1 += bu * s1;
        av0 += bv * s0; av1 += bv * s1;
    }

    int r0 = win_r0(y0);
    #pragma unroll
    for (int r = 0; r < 2; ++r) {
        int yi = y0 + 2 * h + r;
        float du = r ? au1 : au0;
        float dv = r ? av1 : av0;
        float xn = fminf(fmaxf((float)x - scale * du, 0.0f), (float)(NN - 1));
        float yn = (float)yi - scale * dv;
        yn = fminf(fmaxf(yn, (float)yi - 5.0f), (float)yi + 5.0f);  // window guard
        yn = fminf(fmaxf(yn, 0.0f), (float)(NN - 1));
        int xf = (int)floorf(xn), yf = (int)floorf(yn);
        int yc = (int)ceilf(yn);
        float xv = xn - (float)xf;
        float yv = yn - (float)yf;
        u32 oa = (u32)(((yf - r0) << 9) + xf);
        u32 ob = (u32)(((yc - r0) << 9) + xf);
        u32 xq = (u32)__float2int_rn(xv * 65535.0f);
        u32 yq = (u32)__float2int_rn(yv * 65535.0f);
        u32x2 v; v[0] = oa | (ob << 16); v[1] = xq | (yq << 16);
        pk[(yi << 9) + x] = v;
    }
}

// R12-best remap: 8 planes/block, dbuf LDS stage-ahead, pk preloaded once.
// Fixed window -> no strip_tab, no fallback.
__global__ __launch_bounds__(TPB, 2)
void remap_kernel(const float* __restrict__ img,
                  const u32x2* __restrict__ pk,
                  float* __restrict__ out,
                  int planes) {
    __shared__ __align__(16) float rows[2][ROWS_LDS * NN + 4];

    int nb = gridDim.x;
    int bid = blockIdx.x;
    int sid = (bid & 7) * (nb >> 3) + (bid >> 3);   // XCD-bijective swizzle
    int pg    = sid >> 7;
    int strip = sid & 127;

    int t = threadIdx.x;
    int r0 = win_r0(strip * ROWS_OUT);
    int base = ((strip * ROWS_OUT) << 9) + (t << 1);   // x = 2t, 2t+1

    const u32x4* __restrict__ pk4 = (const u32x4*)pk;
    u32x4 pr[ROWS_OUT];
    #pragma unroll
    for (int r = 0; r < ROWS_OUT; ++r) pr[r] = pk4[(base + (r << 9)) >> 1];

    int p0 = pg * PLANES_PER_BLOCK;
    int p1 = p0 + PLANES_PER_BLOCK; if (p1 > planes) p1 = planes;
    const float qs = 1.0f / 65535.0f;

    if (t < 4) { rows[0][ROWS_LDS * NN + t] = 0.f; rows[1][ROWS_LDS * NN + t] = 0.f; }

    const int nbytes = ROWS_LDS << 11;     // 28672
    int wave = t >> 6;
    int lane_goff = t * 16;
    size_t rbo = (size_t)(r0 << 9);

    {
        const char* ipc = (const char*)(img + (size_t)p0 * (NN * NN) + rbo);
        #pragma unroll
        for (int it = 0; it < 7; ++it) {
            int ob = it * (TPB * 16);
            __builtin_amdgcn_global_load_lds(
                (const AS1 void*)(ipc + ob + lane_goff),
                (AS3 void*)((char*)rows[0] + ob + wave * 1024), 16, 0, 0);
        }
    }
    __syncthreads();

    int cur = 0;
    for (int p = p0; p < p1; ++p) {
        if (p + 1 < p1) {
            const char* ipc = (const char*)(img + (size_t)(p + 1) * (NN * NN) + rbo);
            #pragma unroll
            for (int it = 0; it < 7; ++it) {
                int ob = it * (TPB * 16);
                __builtin_amdgcn_global_load_lds(
                    (const AS1 void*)(ipc + ob + lane_goff),
                    (AS3 void*)((char*)rows[cur ^ 1] + ob + wave * 1024), 16, 0, 0);
            }
        }

        const float* __restrict__ rw = rows[cur];
        float* __restrict__ op = out + (size_t)p * (NN * NN);
        #pragma unroll
        for (int r = 0; r < ROWS_OUT; ++r) {
            u32x4 pp = pr[r];
            int oA0 = (int)(pp[0] & 0xFFFFu), oB0 = (int)(pp[0] >> 16);
            float xv0 = (float)(pp[1] & 0xFFFFu) * qs;
            float yv0 = (float)(pp[1] >> 16) * qs;
            int oA1 = (int)(pp[2] & 0xFFFFu), oB1 = (int)(pp[2] >> 16);
            float xv1 = (float)(pp[3] & 0xFFFFu) * qs;
            float yv1 = (float)(pp[3] >> 16) * qs;
            float t0 = (1.f - xv0) * rw[oA0] + xv0 * rw[oA0 + 1];
            float b0 = (1.f - xv0) * rw[oB0] + xv0 * rw[oB0 + 1];
            float t1 = (1.f - xv1) * rw[oA1] + xv1 * rw[oA1 + 1];
            float b1 = (1.f - xv1) * rw[oB1] + xv1 * rw[oB1 + 1];
            f32x2 o;
            o[0] = (1.f - yv0) * t0 + yv0 * b0;
            o[1] = (1.f - yv1) * t1 + yv1 * b1;
            __builtin_nontemporal_store(o, (f32x2*)(op + base + (r << 9)));
        }
        __syncthreads();
        cur ^= 1;
    }
}

extern "C" void kernel_launch(void* const* d_in, const int* in_sizes, int n_in,
                              void* d_out, int out_size, void* d_ws, size_t ws_size,
                              hipStream_t stream) {
    const float* img = (const float*)d_in[0];
    const float* c_u = (const float*)d_in[1];
    const float* c_v = (const float*)d_in[2];
    float* out = (float*)d_out;

    int planes = in_sizes[0] / (NN * NN);   // 96

    float* ws   = (float*)d_ws;
    float* B_u  = ws;
    float* B_v  = B_u + MM * NN;
    u32x2* pk   = (u32x2*)(ws + 2 * MM * NN);

    double log_cut = log((double)MM + 1e-6);
    double T1 = 1.0 / (M_PI * (double)NN * (double)NN * log_cut);
    double T2 = 4.0 / (M_PI * M_PI * M_PI * (double)MM * (double)MM * log_cut);
    if (T2 < T1) T2 = T1;
    double T = 0.5 * (T1 + T2);
    float scale = (float)(sqrt(T) * (double)NN);

    bcoef_kernel<<<NN, 128, 0, stream>>>(c_u, c_v, B_u, B_v);
    field_weights_kernel<<<(NN / ROWS_OUT) * 4, 256, 0, stream>>>(B_u, B_v, scale, pk);

    int strips = NN / ROWS_OUT;                                      // 128
    int groups = (planes + PLANES_PER_BLOCK - 1) / PLANES_PER_BLOCK; // 12
    remap_kernel<<<strips * groups, TPB, 0, stream>>>(img, pk, out, planes);
}

// Round 18
// 88.103 us; speedup vs baseline: 1.1135x; 1.1135x over previous
//
#include <hip/hip_runtime.h>
#include <math.h>

#define NN 512
#define MM 100
#define TPB 256
#define ROWS_OUT 4            // output rows per strip
#define ROWS_LDS 13           // staged input-row window
#define PLANES_PER_BLOCK 8

typedef float f32x2 __attribute__((ext_vector_type(2)));
typedef unsigned int u32;
typedef u32 u32x2 __attribute__((ext_vector_type(2)));
typedef u32 u32x4 __attribute__((ext_vector_type(4)));

#define AS1 __attribute__((address_space(1)))
#define AS3 __attribute__((address_space(3)))

// ws layout: pk[262144 u32x2 = 2 MB] | strip_tab[256 ints]

// ONE kernel for the whole displacement->table pipeline (was bcoef + fw).
// Alternate factorization: A[r][i] = sum_j e(i,j)*c[i][j]*sin_y[r][j]
// (block-local), then field[r][x] = sum_i A[r][i]*sin_x[i], with sin_x
// generated per column by a f64 Chebyshev recurrence (s_{k+1}=2cos(th)s_k -
// s_{k-1}) -- no 400 KB B round-trip, one launch fewer.
__global__ __launch_bounds__(256)
void field_weights_kernel(const float* __restrict__ c_u,
                          const float* __restrict__ c_v,
                          float scale,
                          u32x2* __restrict__ pk,
                          int* __restrict__ strip_tab) {
    __shared__ float sy[ROWS_OUT * MM];
    __shared__ float Au[ROWS_OUT * MM], Av[ROWS_OUT * MM];
    __shared__ int s_mn[4], s_mx[4];
    int t = threadIdx.x;
    int strip = blockIdx.x;
    int y0 = strip * ROWS_OUT;

    // phase 0: sin_y table (400 double sins, spread)
    for (int idx = t; idx < ROWS_OUT * MM; idx += 256) {
        int r = idx / MM, j = idx % MM;
        double arg = M_PI * ((double)(y0 + r) / (double)(NN - 1)) * (double)(j + 1);
        sy[idx] = (float)sin(arg);
    }
    __syncthreads();

    // phase 1: A[r][i] -- 800 outputs (4r x 100i x 2 fields), r fastest so
    // 4 lanes share one c-row (broadcast-friendly)
    for (int idx = t; idx < 2 * ROWS_OUT * MM; idx += 256) {
        int f = idx >= ROWS_OUT * MM;
        int rem = f ? idx - ROWS_OUT * MM : idx;
        int r = rem & 3, i = rem >> 2;
        const float* __restrict__ cf = f ? c_v : c_u;
        int i1 = i + 1;
        float acc = 0.f;
        for (int j = 0; j < MM; ++j) {
            int j1 = j + 1;
            int r2i = i1 * i1 + j1 * j1;
            float w = (r2i <= 10100) ? (1.0f / sqrtf((float)r2i)) : 0.0f;
            acc += cf[i * MM + j] * w * sy[r * MM + j];
        }
        (f ? Av : Au)[r * MM + i] = acc;
    }
    __syncthreads();

    // phase 2: field via per-column sin recurrence; thread owns x = t, t+256
    float au[2][ROWS_OUT] = {}, av[2][ROWS_OUT] = {};
    double s_cur[2], s_prev[2], c2[2];
    #pragma unroll
    for (int c = 0; c < 2; ++c) {
        int x = t + (c << 8);
        double th = M_PI * ((double)x / (double)(NN - 1));
        c2[c] = 2.0 * cos(th);
        s_prev[c] = 0.0;
        s_cur[c] = sin(th);
    }
    for (int i = 0; i < MM; ++i) {
        float A0u = Au[i], A1u = Au[MM + i], A2u = Au[2 * MM + i], A3u = Au[3 * MM + i];
        float A0v = Av[i], A1v = Av[MM + i], A2v = Av[2 * MM + i], A3v = Av[3 * MM + i];
        #pragma unroll
        for (int c = 0; c < 2; ++c) {
            float sx = (float)s_cur[c];
            au[c][0] += A0u * sx; au[c][1] += A1u * sx;
            au[c][2] += A2u * sx; au[c][3] += A3u * sx;
            av[c][0] += A0v * sx; av[c][1] += A1v * sx;
            av[c][2] += A2v * sx; av[c][3] += A3v * sx;
            double nxt = c2[c] * s_cur[c] - s_prev[c];
            s_prev[c] = s_cur[c]; s_cur[c] = nxt;
        }
    }

    // epilogue: bilinear offsets/weights + window reduce + pack (R12-exact)
    float xvq[8], yvq[8];
    int offA[8], offB[8];
    int myf = NN, Myc = -1;
    #pragma unroll
    for (int i = 0; i < 8; ++i) {
        int c = i & 1, r = i >> 1;
        int xi = (c << 8) + t;
        int yi = y0 + r;
        float xn = fminf(fmaxf((float)xi - scale * au[c][r], 0.0f), (float)(NN - 1));
        float yn = fminf(fmaxf((float)yi - scale * av[c][r], 0.0f), (float)(NN - 1));
        int xf = (int)floorf(xn), yf = (int)floorf(yn);
        int yc = (int)ceilf(yn);
        xvq[i] = xn - (float)xf;
        yvq[i] = yn - (float)yf;
        offA[i] = (yf << 9) + xf;
        offB[i] = (yc << 9) + xf;
        myf = min(myf, yf);
        Myc = max(Myc, yc);
    }

    for (int d = 32; d; d >>= 1) {
        myf = min(myf, __shfl_xor(myf, d));
        Myc = max(Myc, __shfl_xor(Myc, d));
    }
    int wid = t >> 6;
    if ((t & 63) == 0) { s_mn[wid] = myf; s_mx[wid] = Myc; }
    __syncthreads();
    int r0 = min(min(s_mn[0], s_mn[1]), min(s_mn[2], s_mn[3]));
    int nr = max(max(s_mx[0], s_mx[1]), max(s_mx[2], s_mx[3])) - r0 + 1;
    if (t == 0) { strip_tab[2 * strip] = r0; strip_tab[2 * strip + 1] = nr; }

    int rb = r0 << 9;
    #pragma unroll
    for (int i = 0; i < 8; ++i) {
        int pix = ((y0 + (i >> 1)) << 9) + ((i & 1) << 8) + t;
        u32 oa = (u32)(offA[i] - rb);
        u32 ob = (u32)(offB[i] - rb);
        u32 xq = (u32)__float2int_rn(xvq[i] * 65535.0f);
        u32 yq = (u32)__float2int_rn(yvq[i] * 65535.0f);
        u32x2 v; v[0] = oa | (ob << 16); v[1] = xq | (yq << 16);
        pk[pix] = v;
    }
}

// R12-exact remap (best measured: 59.9 us): 8 planes/block, dbuf LDS
// stage-ahead, pk preloaded once, NT stores.
__global__ __launch_bounds__(TPB, 3)
void remap_kernel(const float* __restrict__ img,
                  const u32x2* __restrict__ pk,
                  const int* __restrict__ strip_tab,
                  float* __restrict__ out,
                  int planes) {
    __shared__ __align__(16) float rows[2][ROWS_LDS * NN + 4];

    int nb = gridDim.x;
    int bid = blockIdx.x;
    int sid = (bid & 7) * (nb >> 3) + (bid >> 3);   // XCD-bijective swizzle
    int pg    = sid >> 7;
    int strip = sid & 127;

    int t = threadIdx.x;
    int r0 = strip_tab[2 * strip];
    int nr = strip_tab[2 * strip + 1];
    int base = ((strip * ROWS_OUT) << 9) + (t << 1);   // x = 2t, 2t+1

    const u32x4* __restrict__ pk4 = (const u32x4*)pk;
    u32x4 pr[ROWS_OUT];
    #pragma unroll
    for (int r = 0; r < ROWS_OUT; ++r) pr[r] = pk4[(base + (r << 9)) >> 1];

    int p0 = pg * PLANES_PER_BLOCK;
    int p1 = p0 + PLANES_PER_BLOCK; if (p1 > planes) p1 = planes;
    const float qs = 1.0f / 65535.0f;

    if (nr <= ROWS_LDS) {
        if (t == 0) { rows[0][nr * NN] = 0.f; rows[1][nr * NN] = 0.f; }

        int nbytes = nr << 11;
        int wave = t >> 6;
        int lane_goff = t * 16;
        size_t rbo = (size_t)(r0 << 9);

        {
            const char* ipc = (const char*)(img + (size_t)p0 * (NN * NN) + rbo);
            for (int ob = 0; ob < nbytes; ob += TPB * 16) {
                if (ob + wave * 1024 < nbytes) {
                    __builtin_amdgcn_global_load_lds(
                        (const AS1 void*)(ipc + ob + lane_goff),
                        (AS3 void*)((char*)rows[0] + ob + wave * 1024), 16, 0, 0);
                }
            }
        }
        __syncthreads();

        int cur = 0;
        for (int p = p0; p < p1; ++p) {
            if (p + 1 < p1) {
                const char* ipc = (const char*)(img + (size_t)(p + 1) * (NN * NN) + rbo);
                for (int ob = 0; ob < nbytes; ob += TPB * 16) {
                    if (ob + wave * 1024 < nbytes) {
                        __builtin_amdgcn_global_load_lds(
                            (const AS1 void*)(ipc + ob + lane_goff),
                            (AS3 void*)((char*)rows[cur ^ 1] + ob + wave * 1024), 16, 0, 0);
                    }
                }
            }

            const float* __restrict__ rw = rows[cur];
            float* __restrict__ op = out + (size_t)p * (NN * NN);
            #pragma unroll
            for (int r = 0; r < ROWS_OUT; ++r) {
                u32x4 pp = pr[r];
                int oA0 = (int)(pp[0] & 0xFFFFu), oB0 = (int)(pp[0] >> 16);
                float xv0 = (float)(pp[1] & 0xFFFFu) * qs;
                float yv0 = (float)(pp[1] >> 16) * qs;
                int oA1 = (int)(pp[2] & 0xFFFFu), oB1 = (int)(pp[2] >> 16);
                float xv1 = (float)(pp[3] & 0xFFFFu) * qs;
                float yv1 = (float)(pp[3] >> 16) * qs;
                float t0 = (1.f - xv0) * rw[oA0] + xv0 * rw[oA0 + 1];
                float b0 = (1.f - xv0) * rw[oB0] + xv0 * rw[oB0 + 1];
                float t1 = (1.f - xv1) * rw[oA1] + xv1 * rw[oA1 + 1];
                float b1 = (1.f - xv1) * rw[oB1] + xv1 * rw[oB1 + 1];
                f32x2 o;
                o[0] = (1.f - yv0) * t0 + yv0 * b0;
                o[1] = (1.f - yv1) * t1 + yv1 * b1;
                __builtin_nontemporal_store(o, (f32x2*)(op + base + (r << 9)));
            }
            __syncthreads();
            cur ^= 1;
        }
    } else {
        int rb = r0 << 9;
        for (int p = p0; p < p1; ++p) {
            const float* __restrict__ ip = img + (size_t)p * (NN * NN);
            float* __restrict__ op = out + (size_t)p * (NN * NN);
            #pragma unroll
            for (int r = 0; r < ROWS_OUT; ++r) {
                u32x4 pp = pr[r];
                int a0 = (int)(pp[0] & 0xFFFFu) + rb, b0i = (int)(pp[0] >> 16) + rb;
                float xv0 = (float)(pp[1] & 0xFFFFu) * qs;
                float yv0 = (float)(pp[1] >> 16) * qs;
                int a1 = (int)(pp[2] & 0xFFFFu) + rb, b1i = (int)(pp[2] >> 16) + rb;
                float xv1 = (float)(pp[3] & 0xFFFFu) * qs;
                float yv1 = (float)(pp[3] >> 16) * qs;
                int e0 = ((a0 & 511) == 511) ? 0 : 1;
                int e1 = ((a1 & 511) == 511) ? 0 : 1;
                float t0 = (1.f - xv0) * ip[a0] + xv0 * ip[a0 + e0];
                float bo0 = (1.f - xv0) * ip[b0i] + xv0 * ip[b0i + e0];
                float t1 = (1.f - xv1) * ip[a1] + xv1 * ip[a1 + e1];
                float bo1 = (1.f - xv1) * ip[b1i] + xv1 * ip[b1i + e1];
                f32x2 o;
                o[0] = (1.f - yv0) * t0 + yv0 * bo0;
                o[1] = (1.f - yv1) * t1 + yv1 * bo1;
                __builtin_nontemporal_store(o, (f32x2*)(op + base + (r << 9)));
            }
        }
    }
}

extern "C" void kernel_launch(void* const* d_in, const int* in_sizes, int n_in,
                              void* d_out, int out_size, void* d_ws, size_t ws_size,
                              hipStream_t stream) {
    const float* img = (const float*)d_in[0];
    const float* c_u = (const float*)d_in[1];
    const float* c_v = (const float*)d_in[2];
    float* out = (float*)d_out;

    int planes = in_sizes[0] / (NN * NN);   // 96

    float* ws   = (float*)d_ws;
    u32x2* pk   = (u32x2*)ws;                            // 2 MB
    int* strip_tab = (int*)(ws + 2 * NN * NN);           // 256 ints

    double log_cut = log((double)MM + 1e-6);
    double T1 = 1.0 / (M_PI * (double)NN * (double)NN * log_cut);
    double T2 = 4.0 / (M_PI * M_PI * M_PI * (double)MM * (double)MM * log_cut);
    if (T2 < T1) T2 = T1;
    double T = 0.5 * (T1 + T2);
    float scale = (float)(sqrt(T) * (double)NN);

    field_weights_kernel<<<NN / ROWS_OUT, 256, 0, stream>>>(c_u, c_v, scale,
                                                            pk, strip_tab);

    int strips = NN / ROWS_OUT;                                      // 128
    int groups = (planes + PLANES_PER_BLOCK - 1) / PLANES_PER_BLOCK; // 12
    remap_kernel<<<strips * groups, TPB, 0, stream>>>(img, pk, strip_tab,
                                                      out, planes);
}

// Round 19
// 81.586 us; speedup vs baseline: 1.2025x; 1.0799x over previous
//
#include <hip/hip_runtime.h>
#include <math.h>

#define NN 512
#define MM 100
#define TPB 256
#define ROWS_OUT 4            // output rows per strip
#define ROWS_LDS 13           // staged input-row window
#define PLANES_PER_BLOCK 8

typedef float f32x2 __attribute__((ext_vector_type(2)));
typedef unsigned int u32;
typedef u32 u32x2 __attribute__((ext_vector_type(2)));
typedef u32 u32x4 __attribute__((ext_vector_type(4)));

#define AS1 __attribute__((address_space(1)))
#define AS3 __attribute__((address_space(3)))

// ws layout: pk[262144 u32x2 = 2 MB] | strip_tab[256 ints]

// Fused displacement->table kernel (one launch). Doubles as the
// drain-absorber: it runs at near-zero HBM BW while the PREVIOUS replay's
// 100 MB output drains, so remap starts with clean HBM (R18 discovery:
// remap 60 -> ~25 us when preceded by a quiet period).
// Phase 1 unrolled x4 w/ independent accumulators (R18's 62us was serial
// load->FMA chains); phase 2 unrolled x2.
__global__ __launch_bounds__(256)
void field_weights_kernel(const float* __restrict__ c_u,
                          const float* __restrict__ c_v,
                          float scale,
                          u32x2* __restrict__ pk,
                          int* __restrict__ strip_tab) {
    __shared__ float sy[ROWS_OUT * MM];
    __shared__ float Au[ROWS_OUT * MM], Av[ROWS_OUT * MM];
    __shared__ int s_mn[4], s_mx[4];
    int t = threadIdx.x;
    int strip = blockIdx.x;
    int y0 = strip * ROWS_OUT;

    // phase 0: sin_y table (400 f64 sins, spread over threads)
    for (int idx = t; idx < ROWS_OUT * MM; idx += 256) {
        int r = idx / MM, j = idx % MM;
        double arg = M_PI * ((double)(y0 + r) / (double)(NN - 1)) * (double)(j + 1);
        sy[idx] = (float)sin(arg);
    }
    __syncthreads();

    // phase 1: A[r][i] = sum_j e(i,j)*c[i][j]*sy[r][j]
    for (int idx = t; idx < 2 * ROWS_OUT * MM; idx += 256) {
        int f = idx >= ROWS_OUT * MM;
        int rem = f ? idx - ROWS_OUT * MM : idx;
        int r = rem & 3, i = rem >> 2;
        const float* __restrict__ cf = (f ? c_v : c_u) + i * MM;
        const float* __restrict__ syr = sy + r * MM;
        int i2 = (i + 1) * (i + 1);
        float a0 = 0.f, a1 = 0.f, a2 = 0.f, a3 = 0.f;
        #pragma unroll
        for (int j = 0; j < MM; j += 4) {
            int j1 = j + 1, j2 = j + 2, j3 = j + 3, j4 = j + 4;
            int q0 = i2 + j1 * j1, q1 = i2 + j2 * j2;
            int q2 = i2 + j3 * j3, q3 = i2 + j4 * j4;
            float w0 = (q0 <= 10100) ? (1.0f / sqrtf((float)q0)) : 0.0f;
            float w1 = (q1 <= 10100) ? (1.0f / sqrtf((float)q1)) : 0.0f;
            float w2 = (q2 <= 10100) ? (1.0f / sqrtf((float)q2)) : 0.0f;
            float w3 = (q3 <= 10100) ? (1.0f / sqrtf((float)q3)) : 0.0f;
            a0 += cf[j]     * w0 * syr[j];
            a1 += cf[j + 1] * w1 * syr[j + 1];
            a2 += cf[j + 2] * w2 * syr[j + 2];
            a3 += cf[j + 3] * w3 * syr[j + 3];
        }
        (f ? Av : Au)[r * MM + i] = (a0 + a1) + (a2 + a3);
    }
    __syncthreads();

    // phase 2: field via per-column f64 Chebyshev sin recurrence
    float au[2][ROWS_OUT] = {}, av[2][ROWS_OUT] = {};
    double s_cur[2], s_prev[2], c2[2];
    #pragma unroll
    for (int c = 0; c < 2; ++c) {
        int x = t + (c << 8);
        double th = M_PI * ((double)x / (double)(NN - 1));
        c2[c] = 2.0 * cos(th);
        s_prev[c] = 0.0;
        s_cur[c] = sin(th);
    }
    #pragma unroll 2
    for (int i = 0; i < MM; ++i) {
        float A0u = Au[i], A1u = Au[MM + i], A2u = Au[2 * MM + i], A3u = Au[3 * MM + i];
        float A0v = Av[i], A1v = Av[MM + i], A2v = Av[2 * MM + i], A3v = Av[3 * MM + i];
        #pragma unroll
        for (int c = 0; c < 2; ++c) {
            float sx = (float)s_cur[c];
            au[c][0] += A0u * sx; au[c][1] += A1u * sx;
            au[c][2] += A2u * sx; au[c][3] += A3u * sx;
            av[c][0] += A0v * sx; av[c][1] += A1v * sx;
            av[c][2] += A2v * sx; av[c][3] += A3v * sx;
            double nxt = c2[c] * s_cur[c] - s_prev[c];
            s_prev[c] = s_cur[c]; s_cur[c] = nxt;
        }
    }

    // epilogue: bilinear offsets/weights + window reduce + pack
    float xvq[8], yvq[8];
    int offA[8], offB[8];
    int myf = NN, Myc = -1;
    #pragma unroll
    for (int i = 0; i < 8; ++i) {
        int c = i & 1, r = i >> 1;
        int xi = (c << 8) + t;
        int yi = y0 + r;
        float xn = fminf(fmaxf((float)xi - scale * au[c][r], 0.0f), (float)(NN - 1));
        float yn = fminf(fmaxf((float)yi - scale * av[c][r], 0.0f), (float)(NN - 1));
        int xf = (int)floorf(xn), yf = (int)floorf(yn);
        int yc = (int)ceilf(yn);
        xvq[i] = xn - (float)xf;
        yvq[i] = yn - (float)yf;
        offA[i] = (yf << 9) + xf;
        offB[i] = (yc << 9) + xf;
        myf = min(myf, yf);
        Myc = max(Myc, yc);
    }

    for (int d = 32; d; d >>= 1) {
        myf = min(myf, __shfl_xor(myf, d));
        Myc = max(Myc, __shfl_xor(Myc, d));
    }
    int wid = t >> 6;
    if ((t & 63) == 0) { s_mn[wid] = myf; s_mx[wid] = Myc; }
    __syncthreads();
    int r0 = min(min(s_mn[0], s_mn[1]), min(s_mn[2], s_mn[3]));
    int nr = max(max(s_mx[0], s_mx[1]), max(s_mx[2], s_mx[3])) - r0 + 1;
    if (t == 0) { strip_tab[2 * strip] = r0; strip_tab[2 * strip + 1] = nr; }

    int rb = r0 << 9;
    #pragma unroll
    for (int i = 0; i < 8; ++i) {
        int pix = ((y0 + (i >> 1)) << 9) + ((i & 1) << 8) + t;
        u32 oa = (u32)(offA[i] - rb);
        u32 ob = (u32)(offB[i] - rb);
        u32 xq = (u32)__float2int_rn(xvq[i] * 65535.0f);
        u32 yq = (u32)__float2int_rn(yvq[i] * 65535.0f);
        u32x2 v; v[0] = oa | (ob << 16); v[1] = xq | (yq << 16);
        pk[pix] = v;
    }
}

// R12-exact remap: 8 planes/block, dbuf LDS stage-ahead, pk preloaded once,
// NT stores. Runs at ~6.6 TB/s (24-26 us) when HBM is drain-free (R18).
__global__ __launch_bounds__(TPB, 3)
void remap_kernel(const float* __restrict__ img,
                  const u32x2* __restrict__ pk,
                  const int* __restrict__ strip_tab,
                  float* __restrict__ out,
                  int planes) {
    __shared__ __align__(16) float rows[2][ROWS_LDS * NN + 4];

    int nb = gridDim.x;
    int bid = blockIdx.x;
    int sid = (bid & 7) * (nb >> 3) + (bid >> 3);   // XCD-bijective swizzle
    int pg    = sid >> 7;
    int strip = sid & 127;

    int t = threadIdx.x;
    int r0 = strip_tab[2 * strip];
    int nr = strip_tab[2 * strip + 1];
    int base = ((strip * ROWS_OUT) << 9) + (t << 1);   // x = 2t, 2t+1

    const u32x4* __restrict__ pk4 = (const u32x4*)pk;
    u32x4 pr[ROWS_OUT];
    #pragma unroll
    for (int r = 0; r < ROWS_OUT; ++r) pr[r] = pk4[(base + (r << 9)) >> 1];

    int p0 = pg * PLANES_PER_BLOCK;
    int p1 = p0 + PLANES_PER_BLOCK; if (p1 > planes) p1 = planes;
    const float qs = 1.0f / 65535.0f;

    if (nr <= ROWS_LDS) {
        if (t == 0) { rows[0][nr * NN] = 0.f; rows[1][nr * NN] = 0.f; }

        int nbytes = nr << 11;
        int wave = t >> 6;
        int lane_goff = t * 16;
        size_t rbo = (size_t)(r0 << 9);

        {
            const char* ipc = (const char*)(img + (size_t)p0 * (NN * NN) + rbo);
            for (int ob = 0; ob < nbytes; ob += TPB * 16) {
                if (ob + wave * 1024 < nbytes) {
                    __builtin_amdgcn_global_load_lds(
                        (const AS1 void*)(ipc + ob + lane_goff),
                        (AS3 void*)((char*)rows[0] + ob + wave * 1024), 16, 0, 0);
                }
            }
        }
        __syncthreads();

        int cur = 0;
        for (int p = p0; p < p1; ++p) {
            if (p + 1 < p1) {
                const char* ipc = (const char*)(img + (size_t)(p + 1) * (NN * NN) + rbo);
                for (int ob = 0; ob < nbytes; ob += TPB * 16) {
                    if (ob + wave * 1024 < nbytes) {
                        __builtin_amdgcn_global_load_lds(
                            (const AS1 void*)(ipc + ob + lane_goff),
                            (AS3 void*)((char*)rows[cur ^ 1] + ob + wave * 1024), 16, 0, 0);
                    }
                }
            }

            const float* __restrict__ rw = rows[cur];
            float* __restrict__ op = out + (size_t)p * (NN * NN);
            #pragma unroll
            for (int r = 0; r < ROWS_OUT; ++r) {
                u32x4 pp = pr[r];
                int oA0 = (int)(pp[0] & 0xFFFFu), oB0 = (int)(pp[0] >> 16);
                float xv0 = (float)(pp[1] & 0xFFFFu) * qs;
                float yv0 = (float)(pp[1] >> 16) * qs;
                int oA1 = (int)(pp[2] & 0xFFFFu), oB1 = (int)(pp[2] >> 16);
                float xv1 = (float)(pp[3] & 0xFFFFu) * qs;
                float yv1 = (float)(pp[3] >> 16) * qs;
                float t0 = (1.f - xv0) * rw[oA0] + xv0 * rw[oA0 + 1];
                float b0 = (1.f - xv0) * rw[oB0] + xv0 * rw[oB0 + 1];
                float t1 = (1.f - xv1) * rw[oA1] + xv1 * rw[oA1 + 1];
                float b1 = (1.f - xv1) * rw[oB1] + xv1 * rw[oB1 + 1];
                f32x2 o;
                o[0] = (1.f - yv0) * t0 + yv0 * b0;
                o[1] = (1.f - yv1) * t1 + yv1 * b1;
                __builtin_nontemporal_store(o, (f32x2*)(op + base + (r << 9)));
            }
            __syncthreads();
            cur ^= 1;
        }
    } else {
        int rb = r0 << 9;
        for (int p = p0; p < p1; ++p) {
            const float* __restrict__ ip = img + (size_t)p * (NN * NN);
            float* __restrict__ op = out + (size_t)p * (NN * NN);
            #pragma unroll
            for (int r = 0; r < ROWS_OUT; ++r) {
                u32x4 pp = pr[r];
                int a0 = (int)(pp[0] & 0xFFFFu) + rb, b0i = (int)(pp[0] >> 16) + rb;
                float xv0 = (float)(pp[1] & 0xFFFFu) * qs;
                float yv0 = (float)(pp[1] >> 16) * qs;
                int a1 = (int)(pp[2] & 0xFFFFu) + rb, b1i = (int)(pp[2] >> 16) + rb;
                float xv1 = (float)(pp[3] & 0xFFFFu) * qs;
                float yv1 = (float)(pp[3] >> 16) * qs;
                int e0 = ((a0 & 511) == 511) ? 0 : 1;
                int e1 = ((a1 & 511) == 511) ? 0 : 1;
                float t0 = (1.f - xv0) * ip[a0] + xv0 * ip[a0 + e0];
                float bo0 = (1.f - xv0) * ip[b0i] + xv0 * ip[b0i + e0];
                float t1 = (1.f - xv1) * ip[a1] + xv1 * ip[a1 + e1];
                float bo1 = (1.f - xv1) * ip[b1i] + xv1 * ip[b1i + e1];
                f32x2 o;
                o[0] = (1.f - yv0) * t0 + yv0 * bo0;
                o[1] = (1.f - yv1) * t1 + yv1 * bo1;
                __builtin_nontemporal_store(o, (f32x2*)(op + base + (r << 9)));
            }
        }
    }
}

extern "C" void kernel_launch(void* const* d_in, const int* in_sizes, int n_in,
                              void* d_out, int out_size, void* d_ws, size_t ws_size,
                              hipStream_t stream) {
    const float* img = (const float*)d_in[0];
    const float* c_u = (const float*)d_in[1];
    const float* c_v = (const float*)d_in[2];
    float* out = (float*)d_out;

    int planes = in_sizes[0] / (NN * NN);   // 96

    float* ws   = (float*)d_ws;
    u32x2* pk   = (u32x2*)ws;                            // 2 MB
    int* strip_tab = (int*)(ws + 2 * NN * NN);           // 256 ints

    double log_cut = log((double)MM + 1e-6);
    double T1 = 1.0 / (M_PI * (double)NN * (double)NN * log_cut);
    double T2 = 4.0 / (M_PI * M_PI * M_PI * (double)MM * (double)MM * log_cut);
    if (T2 < T1) T2 = T1;
    double T = 0.5 * (T1 + T2);
    float scale = (float)(sqrt(T) * (double)NN);

    field_weights_kernel<<<NN / ROWS_OUT, 256, 0, stream>>>(c_u, c_v, scale,
                                                            pk, strip_tab);

    int strips = NN / ROWS_OUT;                                      // 128
    int groups = (planes + PLANES_PER_BLOCK - 1) / PLANES_PER_BLOCK; // 12
    remap_kernel<<<strips * groups, TPB, 0, stream>>>(img, pk, strip_tab,
                                                      out, planes);
}